// Round 5
// baseline (1164.762 us; speedup 1.0000x reference)
//
#include <hip/hip_runtime.h>

// TinyLlamaBlock on MI355X (gfx950).
// Inputs fp32 (probe-confirmed R3), OUTPUT fp32 (R4 diagnosis: spot-checked
// pipeline correct, mismatch was writing bf16 into an fp32 d_out).
// Internal compute in bf16 via v_mfma_f32_16x16x32_bf16, fp32 accumulate.
//
// Workspace (needs 67.1 MB; R4 confirmed ws_size >= this):
//   [0,        50331648)  qkv bf16 [4096][6144]  cols [0,2048)=Q (later n2),
//                         [2048,4096)=K, [4096,6144)=V (later ctx)
//   [50331648, 67108864)  vT  bf16 [32][128][2048]  (later x1 bf16 [4096][2048])
// n1 bf16 [4096][2048] lives in d_out (dead before final GEMM rewrites d_out).

typedef unsigned short ushort_t;
typedef __attribute__((ext_vector_type(8))) short short8;
typedef __attribute__((ext_vector_type(4))) float floatx4;

__device__ __forceinline__ ushort_t f2bf(float f) {
  union { float f; unsigned u; } v; v.f = f;
  unsigned r = v.u + 0x7fffu + ((v.u >> 16) & 1u);  // RNE
  return (ushort_t)(r >> 16);
}
__device__ __forceinline__ float bf2f(unsigned h) {
  union { unsigned u; float f; } v; v.u = h << 16; return v.f;
}

// ---------------------------------------------------------------------------
// RMSNorm [4096][2048] -> bf16 (strided out). XBF: input bf16 (internal x1)
// else fp32 (external x). g is fp32.
// ---------------------------------------------------------------------------
template <bool XBF>
__global__ __launch_bounds__(256) void rmsnorm_kernel(
    const void* __restrict__ xv, const float* __restrict__ g,
    ushort_t* __restrict__ out, int out_ld) {
  const int row = blockIdx.x, t = threadIdx.x;
  float v[8];
  if (XBF) {
    uint4 raw = *(const uint4*)((const ushort_t*)xv + (size_t)row * 2048 + t * 8);
    v[0] = bf2f(raw.x & 0xffffu); v[1] = bf2f(raw.x >> 16);
    v[2] = bf2f(raw.y & 0xffffu); v[3] = bf2f(raw.y >> 16);
    v[4] = bf2f(raw.z & 0xffffu); v[5] = bf2f(raw.z >> 16);
    v[6] = bf2f(raw.w & 0xffffu); v[7] = bf2f(raw.w >> 16);
  } else {
    const float* xr = (const float*)xv + (size_t)row * 2048 + t * 8;
    float4 a = *(const float4*)xr;
    float4 b = *(const float4*)(xr + 4);
    v[0] = a.x; v[1] = a.y; v[2] = a.z; v[3] = a.w;
    v[4] = b.x; v[5] = b.y; v[6] = b.z; v[7] = b.w;
  }
  float ss = 0.f;
#pragma unroll
  for (int i = 0; i < 8; ++i) ss += v[i] * v[i];
#pragma unroll
  for (int m = 32; m >= 1; m >>= 1) ss += __shfl_xor(ss, m, 64);
  __shared__ float red[4];
  if ((t & 63) == 0) red[t >> 6] = ss;
  __syncthreads();
  float rs = rsqrtf((red[0] + red[1] + red[2] + red[3]) * (1.0f / 2048.0f) + 1e-5f);
  const float* gp = g + t * 8;
  float4 ga = *(const float4*)gp;
  float4 gb = *(const float4*)(gp + 4);
  float gv[8] = {ga.x, ga.y, ga.z, ga.w, gb.x, gb.y, gb.z, gb.w};
  union { ushort_t u16[8]; uint4 u; } p;
#pragma unroll
  for (int i = 0; i < 8; ++i) p.u16[i] = f2bf(v[i] * rs * gv[i]);
  *(uint4*)&out[(size_t)row * out_ld + t * 8] = p.u;
}

// ---------------------------------------------------------------------------
// GEMM: C[M,N] = A[M,K](bf16, lda) * B[K,N](fp32, ldb — natural (k,n) layout,
// transposed+converted to bf16 during LDS staging), 128x128 tile, BK=32.
// MODE 0: C bf16 (ldc) = acc
// MODE 1: C bf16 (ldc) = resid(fp32, ldr) + acc
// MODE 2: C fp32 (ldc) = resid(bf16, ldr) + acc + bias(fp32)[col]
// ---------------------------------------------------------------------------
template <int MODE>
__global__ __launch_bounds__(256, 2) void gemm_nt(
    const ushort_t* A, int lda, const float* B, int ldb,
    void* Cv, int ldc, const void* resid, int ldr,
    const float* bias, int M, int N, int K) {
  __shared__ __align__(16) ushort_t As[128][40];
  __shared__ __align__(16) ushort_t Bs[128][40];  // [n][k]
  const int t = threadIdx.x;
  const int wid = t >> 6, lane = t & 63;
  const int l15 = lane & 15, quad = lane >> 4;
  const int m0 = blockIdx.y * 128, n0 = blockIdx.x * 128;
  const int wm = (wid >> 1) * 64, wn = (wid & 1) * 64;
  const int sr = t >> 2, so = (t & 3) * 8;

  floatx4 acc[4][4];
#pragma unroll
  for (int i = 0; i < 4; ++i)
#pragma unroll
    for (int j = 0; j < 4; ++j) acc[i][j] = (floatx4){0.f, 0.f, 0.f, 0.f};

  for (int k0 = 0; k0 < K; k0 += 32) {
    __syncthreads();
    *(uint4*)&As[sr][so]      = *(const uint4*)&A[(size_t)(m0 + sr) * lda + k0 + so];
    *(uint4*)&As[sr + 64][so] = *(const uint4*)&A[(size_t)(m0 + sr + 64) * lda + k0 + so];
#pragma unroll
    for (int i = 0; i < 4; ++i) {
      int c = t + 256 * i;
      int r = c >> 5;            // k-row 0..31
      int o = (c & 31) * 4;      // n offset 0..124
      float4 w = *(const float4*)&B[(size_t)(k0 + r) * ldb + n0 + o];
      Bs[o + 0][r] = f2bf(w.x);
      Bs[o + 1][r] = f2bf(w.y);
      Bs[o + 2][r] = f2bf(w.z);
      Bs[o + 3][r] = f2bf(w.w);
    }
    __syncthreads();

    short8 af[4], bf[4];
#pragma unroll
    for (int i = 0; i < 4; ++i)
      af[i] = *(const short8*)&As[wm + i * 16 + l15][quad * 8];
#pragma unroll
    for (int j = 0; j < 4; ++j)
      bf[j] = *(const short8*)&Bs[wn + j * 16 + l15][quad * 8];
#pragma unroll
    for (int i = 0; i < 4; ++i)
#pragma unroll
      for (int j = 0; j < 4; ++j)
        acc[i][j] = __builtin_amdgcn_mfma_f32_16x16x32_bf16(af[i], bf[j],
                                                            acc[i][j], 0, 0, 0);
  }

#pragma unroll
  for (int i = 0; i < 4; ++i)
#pragma unroll
    for (int j = 0; j < 4; ++j)
#pragma unroll
      for (int r = 0; r < 4; ++r) {
        int row = m0 + wm + i * 16 + quad * 4 + r;
        int col = n0 + wn + j * 16 + l15;
        float v = acc[i][j][r];
        if (MODE == 0) {
          ((ushort_t*)Cv)[(size_t)row * ldc + col] = f2bf(v);
        } else if (MODE == 1) {
          float rv = ((const float*)resid)[(size_t)row * ldr + col];
          ((ushort_t*)Cv)[(size_t)row * ldc + col] = f2bf(rv + v);
        } else {
          float rv = bf2f(((const ushort_t*)resid)[(size_t)row * ldr + col]);
          ((float*)Cv)[(size_t)row * ldc + col] = rv + v + bias[col];
        }
      }
}

// ---------------------------------------------------------------------------
// Transpose V section of qkv -> vT[b*16+h][d][s]  (bf16)
// ---------------------------------------------------------------------------
__global__ __launch_bounds__(256) void transpose_v_kernel(
    const ushort_t* __restrict__ qkv, ushort_t* __restrict__ vT) {
  __shared__ __align__(16) ushort_t tile[64][72];  // [d][s]
  const int t = threadIdx.x;
  const int s0 = blockIdx.x * 64, d0 = blockIdx.y * 64;
  const int bh = blockIdx.z, b = bh >> 4, h = bh & 15;
#pragma unroll
  for (int i = 0; i < 2; ++i) {
    int c = t + 256 * i, r = c >> 3, o = (c & 7) * 8;
    uint4 raw = *(const uint4*)&qkv[(size_t)(b * 2048 + s0 + r) * 6144 + 4096 +
                                    h * 128 + d0 + o];
    tile[o + 0][r] = (ushort_t)(raw.x & 0xffffu);
    tile[o + 1][r] = (ushort_t)(raw.x >> 16);
    tile[o + 2][r] = (ushort_t)(raw.y & 0xffffu);
    tile[o + 3][r] = (ushort_t)(raw.y >> 16);
    tile[o + 4][r] = (ushort_t)(raw.z & 0xffffu);
    tile[o + 5][r] = (ushort_t)(raw.z >> 16);
    tile[o + 6][r] = (ushort_t)(raw.w & 0xffffu);
    tile[o + 7][r] = (ushort_t)(raw.w >> 16);
  }
  __syncthreads();
#pragma unroll
  for (int i = 0; i < 2; ++i) {
    int c = t + 256 * i, r = c >> 3, o = (c & 7) * 8;
    *(uint4*)&vT[((size_t)bh * 128 + d0 + r) * 2048 + s0 + o] =
        *(const uint4*)&tile[r][o];
  }
}

// ---------------------------------------------------------------------------
// Flash attention (causal). ctx written strided (into qkv's dead V section).
// ---------------------------------------------------------------------------
__global__ __launch_bounds__(256, 2) void attn_kernel(
    const ushort_t* qkv, const ushort_t* vT, ushort_t* ctx, int ldctx) {
  const int S = 2048, LD = 6144, D = 128;
  __shared__ __align__(16) ushort_t Qs[64][136];
  __shared__ __align__(16) ushort_t Ks[64][136];
  __shared__ __align__(16) ushort_t Vt[128][72];
  __shared__ __align__(16) ushort_t Ps[4][16][72];
  const int t = threadIdx.x;
  const int wid = t >> 6, lane = t & 63;
  const int l15 = lane & 15, quad = lane >> 4;
  const int qb = blockIdx.x * 64;
  const int bh = blockIdx.y, b = bh >> 4, h = bh & 15;

#pragma unroll
  for (int i = 0; i < 4; ++i) {
    int c = t + 256 * i, r = c >> 4, o = (c & 15) * 8;
    *(uint4*)&Qs[r][o] =
        *(const uint4*)&qkv[(size_t)(b * S + qb + r) * LD + h * D + o];
  }

  floatx4 accO[8];
#pragma unroll
  for (int i = 0; i < 8; ++i) accO[i] = (floatx4){0.f, 0.f, 0.f, 0.f};
  float m_i[4] = {-1e30f, -1e30f, -1e30f, -1e30f};
  float l_i[4] = {0.f, 0.f, 0.f, 0.f};
  const float sc = 0.08838834764831845f;

  const int nkt = (qb >> 6) + 1;
  for (int kt = 0; kt < nkt; ++kt) {
    const int kb = kt * 64;
    __syncthreads();
#pragma unroll
    for (int i = 0; i < 4; ++i) {
      int c = t + 256 * i, r = c >> 4, o = (c & 15) * 8;
      *(uint4*)&Ks[r][o] =
          *(const uint4*)&qkv[(size_t)(b * S + kb + r) * LD + 2048 + h * D + o];
    }
#pragma unroll
    for (int i = 0; i < 4; ++i) {
      int c = t + 256 * i, r = c >> 3, o = (c & 7) * 8;
      *(uint4*)&Vt[r][o] = *(const uint4*)&vT[((size_t)bh * D + r) * S + kb + o];
    }
    __syncthreads();

    short8 qf[4];
#pragma unroll
    for (int kk = 0; kk < 4; ++kk)
      qf[kk] = *(const short8*)&Qs[wid * 16 + l15][kk * 32 + quad * 8];

    floatx4 sf[4];
#pragma unroll
    for (int jn = 0; jn < 4; ++jn) {
      sf[jn] = (floatx4){0.f, 0.f, 0.f, 0.f};
#pragma unroll
      for (int kk = 0; kk < 4; ++kk) {
        short8 kf = *(const short8*)&Ks[jn * 16 + l15][kk * 32 + quad * 8];
        sf[jn] = __builtin_amdgcn_mfma_f32_16x16x32_bf16(qf[kk], kf, sf[jn], 0, 0, 0);
      }
    }

    const int qrow = qb + wid * 16 + quad * 4;
    float pv[4][4];
#pragma unroll
    for (int jn = 0; jn < 4; ++jn)
#pragma unroll
      for (int r = 0; r < 4; ++r) {
        int col = kb + jn * 16 + l15;
        float s = sf[jn][r] * sc;
        pv[jn][r] = (col <= qrow + r) ? s : -1e30f;
      }

    float alpha[4];
#pragma unroll
    for (int r = 0; r < 4; ++r) {
      float v = fmaxf(fmaxf(pv[0][r], pv[1][r]), fmaxf(pv[2][r], pv[3][r]));
      v = fmaxf(v, __shfl_xor(v, 1, 64));
      v = fmaxf(v, __shfl_xor(v, 2, 64));
      v = fmaxf(v, __shfl_xor(v, 4, 64));
      v = fmaxf(v, __shfl_xor(v, 8, 64));
      float mnew = fmaxf(m_i[r], v);
      alpha[r] = __expf(m_i[r] - mnew);
      m_i[r] = mnew;
    }
#pragma unroll
    for (int jn = 0; jn < 4; ++jn)
#pragma unroll
      for (int r = 0; r < 4; ++r) pv[jn][r] = __expf(pv[jn][r] - m_i[r]);
#pragma unroll
    for (int r = 0; r < 4; ++r) {
      float s = pv[0][r] + pv[1][r] + pv[2][r] + pv[3][r];
      s += __shfl_xor(s, 1, 64);
      s += __shfl_xor(s, 2, 64);
      s += __shfl_xor(s, 4, 64);
      s += __shfl_xor(s, 8, 64);
      l_i[r] = l_i[r] * alpha[r] + s;
    }
#pragma unroll
    for (int jn = 0; jn < 4; ++jn)
#pragma unroll
      for (int r = 0; r < 4; ++r)
        Ps[wid][quad * 4 + r][jn * 16 + l15] = f2bf(pv[jn][r]);
#pragma unroll
    for (int jd = 0; jd < 8; ++jd)
#pragma unroll
      for (int r = 0; r < 4; ++r) accO[jd][r] *= alpha[r];

    __asm__ __volatile__("s_waitcnt lgkmcnt(0)" ::: "memory");

    short8 pf[2];
#pragma unroll
    for (int kk = 0; kk < 2; ++kk)
      pf[kk] = *(const short8*)&Ps[wid][l15][kk * 32 + quad * 8];
#pragma unroll
    for (int jd = 0; jd < 8; ++jd)
#pragma unroll
      for (int kk = 0; kk < 2; ++kk) {
        short8 vf = *(const short8*)&Vt[jd * 16 + l15][kk * 32 + quad * 8];
        accO[jd] = __builtin_amdgcn_mfma_f32_16x16x32_bf16(pf[kk], vf, accO[jd], 0, 0, 0);
      }
  }

#pragma unroll
  for (int jd = 0; jd < 8; ++jd)
#pragma unroll
    for (int r = 0; r < 4; ++r) {
      int row = b * S + qb + wid * 16 + quad * 4 + r;
      int col = h * D + jd * 16 + l15;
      ctx[(size_t)row * ldctx + col] = f2bf(accO[jd][r] / l_i[r]);
    }
}

// ---------------------------------------------------------------------------
extern "C" void kernel_launch(void* const* d_in, const int* in_sizes, int n_in,
                              void* d_out, int out_size, void* d_ws,
                              size_t ws_size, hipStream_t stream) {
  const float* x    = (const float*)d_in[0];
  const float* ln1  = (const float*)d_in[1];
  const float* Wq   = (const float*)d_in[2];
  const float* Wk   = (const float*)d_in[3];
  const float* Wv   = (const float*)d_in[4];
  const float* Wo   = (const float*)d_in[5];
  const float* ln2  = (const float*)d_in[6];
  const float* Wmlp = (const float*)d_in[7];
  const float* bmlp = (const float*)d_in[8];
  float* out = (float*)d_out;   // fp32 output (reference output dtype)

  char* ws = (char*)d_ws;
  ushort_t* qkv = (ushort_t*)(ws + 0);           // [4096][6144]
  ushort_t* vT  = (ushort_t*)(ws + 50331648);    // [32][128][2048]
  ushort_t* n1  = (ushort_t*)d_out;              // [4096][2048] scratch in d_out
  ushort_t* ctx = qkv + 4096;                    // V section, ld 6144
  ushort_t* x1  = vT;                            // bf16 [4096][2048] after attn
  ushort_t* n2  = qkv;                           // Q section, ld 6144

  dim3 blk(256);

  // 1) rmsnorm1: x fp32 -> n1 (bf16, scratch inside d_out)
  rmsnorm_kernel<false><<<dim3(4096), blk, 0, stream>>>(x, ln1, n1, 2048);

  // 2) QKV projections (B staged from natural (k,n) fp32 layout)
  gemm_nt<0><<<dim3(16, 32), blk, 0, stream>>>(n1, 2048, Wq, 2048, qkv + 0, 6144,
                                               nullptr, 0, nullptr, 4096, 2048, 2048);
  gemm_nt<0><<<dim3(16, 32), blk, 0, stream>>>(n1, 2048, Wk, 2048, qkv + 2048, 6144,
                                               nullptr, 0, nullptr, 4096, 2048, 2048);
  gemm_nt<0><<<dim3(16, 32), blk, 0, stream>>>(n1, 2048, Wv, 2048, qkv + 4096, 6144,
                                               nullptr, 0, nullptr, 4096, 2048, 2048);

  // 3) V transpose for attention staging
  transpose_v_kernel<<<dim3(32, 2, 32), blk, 0, stream>>>(qkv, vT);

  // 4) causal flash attention -> ctx (overwrites dead V section)
  attn_kernel<<<dim3(32, 32), blk, 0, stream>>>(qkv, vT, ctx, 6144);

  // 5) out-projection + residual(x fp32) -> x1 bf16 (overwrites dead vT)
  gemm_nt<1><<<dim3(16, 32), blk, 0, stream>>>(ctx, 6144, Wo, 2048, x1, 2048,
                                               x, 2048, nullptr, 4096, 2048, 2048);

  // 6) rmsnorm2: x1 bf16 -> n2 (strided into dead Q section)
  rmsnorm_kernel<true><<<dim3(4096), blk, 0, stream>>>(x1, ln2, n2, 6144);

  // 7) MLP + residual(x1 bf16) + bias -> out fp32
  gemm_nt<2><<<dim3(16, 32), blk, 0, stream>>>(n2, 6144, Wmlp, 2048, out, 2048,
                                               x1, 2048, bmlp, 4096, 2048, 2048);
}

// Round 6
// 609.121 us; speedup vs baseline: 1.9122x; 1.9122x over previous
//
#include <hip/hip_runtime.h>

// TinyLlamaBlock on MI355X (gfx950). Inputs fp32, output fp32 (validated R5).
// Internal compute bf16 via v_mfma_f32_16x16x32_bf16, fp32 accumulate.
// R6: m97-style GEMM (bf16 [n][k] weights + global_load_lds width-16,
// unpadded LDS tiles), attention Q-in-registers + 3 blocks/CU.
//
// Workspace (67.11 MB, proven available in R4):
//   [0, 50331648)        qkv bf16 [4096][6144]: cols [0,2048)=Q (later n2),
//                        [2048,4096)=K (later x1), [4096,6144)=V (later ctx)
//   [50331648, 67108864) R2 16.78 MB, rotating:
//                        WqT/WkT/WvT (8.39 MB each, two live max) -> vT
//                        (16.78) -> WoT (8.39) -> WmlpT (8.39)
// d_out: n1 bf16 [4096][2048] in [0,16.78MB) until QKV GEMMs done; final GEMM
// rewrites all of d_out as fp32.

typedef unsigned short ushort_t;
typedef __attribute__((ext_vector_type(8))) short short8;
typedef __attribute__((ext_vector_type(4))) float floatx4;

__device__ __forceinline__ ushort_t f2bf(float f) {
  union { float f; unsigned u; } v; v.f = f;
  unsigned r = v.u + 0x7fffu + ((v.u >> 16) & 1u);  // RNE
  return (ushort_t)(r >> 16);
}
__device__ __forceinline__ float bf2f(unsigned h) {
  union { unsigned u; float f; } v; v.u = h << 16; return v.f;
}
// async 16B/lane global->LDS; LDS dest = wave-uniform base + lane*16
__device__ __forceinline__ void load16(const ushort_t* g, ushort_t* l) {
  __builtin_amdgcn_global_load_lds(
      (const __attribute__((address_space(1))) unsigned*)g,
      (__attribute__((address_space(3))) unsigned*)l, 16, 0, 0);
}

// ---------------------------------------------------------------------------
// Weight transpose+convert: fp32 [2048][2048] (k,n) -> bf16 [2048][2048] (n,k)
// ---------------------------------------------------------------------------
__global__ __launch_bounds__(256) void transpose_w_kernel(
    const float* __restrict__ src, ushort_t* __restrict__ dst) {
  __shared__ __align__(16) ushort_t tile[64][72];  // [n][k]
  const int t = threadIdx.x;
  const int n0 = blockIdx.x * 64, k0 = blockIdx.y * 64;
#pragma unroll
  for (int i = 0; i < 4; ++i) {
    int c = t + 256 * i;            // 64 k-rows x 16 chunks of 4 floats
    int r = c >> 4, o = (c & 15) * 4;
    float4 raw = *(const float4*)&src[(size_t)(k0 + r) * 2048 + n0 + o];
    tile[o + 0][r] = f2bf(raw.x);
    tile[o + 1][r] = f2bf(raw.y);
    tile[o + 2][r] = f2bf(raw.z);
    tile[o + 3][r] = f2bf(raw.w);
  }
  __syncthreads();
#pragma unroll
  for (int i = 0; i < 2; ++i) {
    int c = t + 256 * i;            // 64 n-rows x 8 chunks of 8 bf16
    int r = c >> 3, o = (c & 7) * 8;
    *(uint4*)&dst[(size_t)(n0 + r) * 2048 + k0 + o] = *(const uint4*)&tile[r][o];
  }
}

// ---------------------------------------------------------------------------
// RMSNorm [4096][2048] -> bf16 (strided in/out). XBF: input bf16 else fp32.
// ---------------------------------------------------------------------------
template <bool XBF>
__global__ __launch_bounds__(256) void rmsnorm_kernel(
    const void* __restrict__ xv, int in_ld, const float* __restrict__ g,
    ushort_t* __restrict__ out, int out_ld) {
  const int row = blockIdx.x, t = threadIdx.x;
  float v[8];
  if (XBF) {
    uint4 raw = *(const uint4*)((const ushort_t*)xv + (size_t)row * in_ld + t * 8);
    v[0] = bf2f(raw.x & 0xffffu); v[1] = bf2f(raw.x >> 16);
    v[2] = bf2f(raw.y & 0xffffu); v[3] = bf2f(raw.y >> 16);
    v[4] = bf2f(raw.z & 0xffffu); v[5] = bf2f(raw.z >> 16);
    v[6] = bf2f(raw.w & 0xffffu); v[7] = bf2f(raw.w >> 16);
  } else {
    const float* xr = (const float*)xv + (size_t)row * in_ld + t * 8;
    float4 a = *(const float4*)xr;
    float4 b = *(const float4*)(xr + 4);
    v[0] = a.x; v[1] = a.y; v[2] = a.z; v[3] = a.w;
    v[4] = b.x; v[5] = b.y; v[6] = b.z; v[7] = b.w;
  }
  float ss = 0.f;
#pragma unroll
  for (int i = 0; i < 8; ++i) ss += v[i] * v[i];
#pragma unroll
  for (int m = 32; m >= 1; m >>= 1) ss += __shfl_xor(ss, m, 64);
  __shared__ float red[4];
  if ((t & 63) == 0) red[t >> 6] = ss;
  __syncthreads();
  float rs = rsqrtf((red[0] + red[1] + red[2] + red[3]) * (1.0f / 2048.0f) + 1e-5f);
  const float* gp = g + t * 8;
  float4 ga = *(const float4*)gp;
  float4 gb = *(const float4*)(gp + 4);
  float gv[8] = {ga.x, ga.y, ga.z, ga.w, gb.x, gb.y, gb.z, gb.w};
  union { ushort_t u16[8]; uint4 u; } p;
#pragma unroll
  for (int i = 0; i < 8; ++i) p.u16[i] = f2bf(v[i] * rs * gv[i]);
  *(uint4*)&out[(size_t)row * out_ld + t * 8] = p.u;
}

// ---------------------------------------------------------------------------
// GEMM m97-style: C[M,N] = A[M,K](bf16, lda) * Bt[N,K](bf16, ldb)^T.
// 128x128 tile, BK=32, unpadded LDS, global_load_lds width-16 staging.
// MODE 0: C bf16 (ldc) = acc
// MODE 1: C bf16 (ldc) = resid(fp32, ldr) + acc
// MODE 2: C fp32 (ldc) = resid(bf16, ldr) + acc + bias(fp32)[col]
// ---------------------------------------------------------------------------
template <int MODE>
__global__ __launch_bounds__(256, 2) void gemm_bt(
    const ushort_t* A, int lda, const ushort_t* Bt, int ldb,
    void* Cv, int ldc, const void* resid, int ldr,
    const float* bias, int M, int N, int K) {
  __shared__ __align__(16) ushort_t As[128][32];
  __shared__ __align__(16) ushort_t Bs[128][32];
  const int t = threadIdx.x;
  const int wid = t >> 6, lane = t & 63;
  const int l15 = lane & 15, quad = lane >> 4;
  const int m0 = blockIdx.y * 128, n0 = blockIdx.x * 128;
  const int wm = (wid >> 1) * 64, wn = (wid & 1) * 64;

  // staging: wave wid covers rows [wid*32, wid*32+32) in two 16-row segments;
  // lane covers row seg+lane/4, k-offset (lane&3)*8  (matches base+lane*16B)
  const int srow = wid * 32 + (lane >> 2);
  const int scol = (lane & 3) * 8;
  const ushort_t* ag0 = &A[(size_t)(m0 + srow) * lda + scol];
  const ushort_t* ag1 = &A[(size_t)(m0 + srow + 16) * lda + scol];
  const ushort_t* bg0 = &Bt[(size_t)(n0 + srow) * ldb + scol];
  const ushort_t* bg1 = &Bt[(size_t)(n0 + srow + 16) * ldb + scol];
  ushort_t* al0 = &As[wid * 32][0];
  ushort_t* al1 = &As[wid * 32 + 16][0];
  ushort_t* bl0 = &Bs[wid * 32][0];
  ushort_t* bl1 = &Bs[wid * 32 + 16][0];

  floatx4 acc[4][4];
#pragma unroll
  for (int i = 0; i < 4; ++i)
#pragma unroll
    for (int j = 0; j < 4; ++j) acc[i][j] = (floatx4){0.f, 0.f, 0.f, 0.f};

  for (int k0 = 0; k0 < K; k0 += 32) {
    __syncthreads();
    load16(ag0 + k0, al0);
    load16(ag1 + k0, al1);
    load16(bg0 + k0, bl0);
    load16(bg1 + k0, bl1);
    __syncthreads();

    short8 af[4], bf[4];
#pragma unroll
    for (int i = 0; i < 4; ++i)
      af[i] = *(const short8*)&As[wm + i * 16 + l15][quad * 8];
#pragma unroll
    for (int j = 0; j < 4; ++j)
      bf[j] = *(const short8*)&Bs[wn + j * 16 + l15][quad * 8];
#pragma unroll
    for (int i = 0; i < 4; ++i)
#pragma unroll
      for (int j = 0; j < 4; ++j)
        acc[i][j] = __builtin_amdgcn_mfma_f32_16x16x32_bf16(af[i], bf[j],
                                                            acc[i][j], 0, 0, 0);
  }

#pragma unroll
  for (int i = 0; i < 4; ++i)
#pragma unroll
    for (int j = 0; j < 4; ++j)
#pragma unroll
      for (int r = 0; r < 4; ++r) {
        int row = m0 + wm + i * 16 + quad * 4 + r;
        int col = n0 + wn + j * 16 + l15;
        float v = acc[i][j][r];
        if (MODE == 0) {
          ((ushort_t*)Cv)[(size_t)row * ldc + col] = f2bf(v);
        } else if (MODE == 1) {
          float rv = ((const float*)resid)[(size_t)row * ldr + col];
          ((ushort_t*)Cv)[(size_t)row * ldc + col] = f2bf(rv + v);
        } else {
          float rv = bf2f(((const ushort_t*)resid)[(size_t)row * ldr + col]);
          ((float*)Cv)[(size_t)row * ldc + col] = rv + v + bias[col];
        }
      }
}

// ---------------------------------------------------------------------------
// Transpose V section of qkv -> vT[b*16+h][d][s]  (bf16)
// ---------------------------------------------------------------------------
__global__ __launch_bounds__(256) void transpose_v_kernel(
    const ushort_t* __restrict__ qkv, ushort_t* __restrict__ vT) {
  __shared__ __align__(16) ushort_t tile[64][72];  // [d][s]
  const int t = threadIdx.x;
  const int s0 = blockIdx.x * 64, d0 = blockIdx.y * 64;
  const int bh = blockIdx.z, b = bh >> 4, h = bh & 15;
#pragma unroll
  for (int i = 0; i < 2; ++i) {
    int c = t + 256 * i, r = c >> 3, o = (c & 7) * 8;
    uint4 raw = *(const uint4*)&qkv[(size_t)(b * 2048 + s0 + r) * 6144 + 4096 +
                                    h * 128 + d0 + o];
    tile[o + 0][r] = (ushort_t)(raw.x & 0xffffu);
    tile[o + 1][r] = (ushort_t)(raw.x >> 16);
    tile[o + 2][r] = (ushort_t)(raw.y & 0xffffu);
    tile[o + 3][r] = (ushort_t)(raw.y >> 16);
    tile[o + 4][r] = (ushort_t)(raw.z & 0xffffu);
    tile[o + 5][r] = (ushort_t)(raw.z >> 16);
    tile[o + 6][r] = (ushort_t)(raw.w & 0xffffu);
    tile[o + 7][r] = (ushort_t)(raw.w >> 16);
  }
  __syncthreads();
#pragma unroll
  for (int i = 0; i < 2; ++i) {
    int c = t + 256 * i, r = c >> 3, o = (c & 7) * 8;
    *(uint4*)&vT[((size_t)bh * 128 + d0 + r) * 2048 + s0 + o] =
        *(const uint4*)&tile[r][o];
  }
}

// ---------------------------------------------------------------------------
// Flash attention (causal). Q fragments from global (no Qs LDS); 45 KB LDS
// -> 3 blocks/CU. qb reversed so diagonal (heavy) blocks launch first.
// ---------------------------------------------------------------------------
__global__ __launch_bounds__(256, 3) void attn_kernel(
    const ushort_t* qkv, const ushort_t* vT, ushort_t* ctx, int ldctx) {
  const int S = 2048, LD = 6144, D = 128;
  __shared__ __align__(16) ushort_t Ks[64][136];
  __shared__ __align__(16) ushort_t Vt[128][72];
  __shared__ __align__(16) ushort_t Ps[4][16][72];
  const int t = threadIdx.x;
  const int wid = t >> 6, lane = t & 63;
  const int l15 = lane & 15, quad = lane >> 4;
  const int qb = (int)(gridDim.x - 1 - blockIdx.x) * 64;  // heavy blocks first
  const int bh = blockIdx.y, b = bh >> 4, h = bh & 15;

  // Q fragments straight from global (one-time, per-wave rows)
  short8 qf[4];
  {
    const ushort_t* qp =
        &qkv[(size_t)(b * S + qb + wid * 16 + l15) * LD + h * D];
#pragma unroll
    for (int kk = 0; kk < 4; ++kk)
      qf[kk] = *(const short8*)&qp[kk * 32 + quad * 8];
  }

  floatx4 accO[8];
#pragma unroll
  for (int i = 0; i < 8; ++i) accO[i] = (floatx4){0.f, 0.f, 0.f, 0.f};
  float m_i[4] = {-1e30f, -1e30f, -1e30f, -1e30f};
  float l_i[4] = {0.f, 0.f, 0.f, 0.f};
  const float sc = 0.08838834764831845f;

  const int nkt = (qb >> 6) + 1;
  for (int kt = 0; kt < nkt; ++kt) {
    const int kb = kt * 64;
    __syncthreads();
#pragma unroll
    for (int i = 0; i < 4; ++i) {
      int c = t + 256 * i, r = c >> 4, o = (c & 15) * 8;
      *(uint4*)&Ks[r][o] =
          *(const uint4*)&qkv[(size_t)(b * S + kb + r) * LD + 2048 + h * D + o];
    }
#pragma unroll
    for (int i = 0; i < 4; ++i) {
      int c = t + 256 * i, r = c >> 3, o = (c & 7) * 8;
      *(uint4*)&Vt[r][o] = *(const uint4*)&vT[((size_t)bh * D + r) * S + kb + o];
    }
    __syncthreads();

    floatx4 sf[4];
#pragma unroll
    for (int jn = 0; jn < 4; ++jn) {
      sf[jn] = (floatx4){0.f, 0.f, 0.f, 0.f};
#pragma unroll
      for (int kk = 0; kk < 4; ++kk) {
        short8 kf = *(const short8*)&Ks[jn * 16 + l15][kk * 32 + quad * 8];
        sf[jn] = __builtin_amdgcn_mfma_f32_16x16x32_bf16(qf[kk], kf, sf[jn], 0, 0, 0);
      }
    }

    const int qrow = qb + wid * 16 + quad * 4;
    float pv[4][4];
#pragma unroll
    for (int jn = 0; jn < 4; ++jn)
#pragma unroll
      for (int r = 0; r < 4; ++r) {
        int col = kb + jn * 16 + l15;
        float s = sf[jn][r] * sc;
        pv[jn][r] = (col <= qrow + r) ? s : -1e30f;
      }

    float alpha[4];
#pragma unroll
    for (int r = 0; r < 4; ++r) {
      float v = fmaxf(fmaxf(pv[0][r], pv[1][r]), fmaxf(pv[2][r], pv[3][r]));
      v = fmaxf(v, __shfl_xor(v, 1, 64));
      v = fmaxf(v, __shfl_xor(v, 2, 64));
      v = fmaxf(v, __shfl_xor(v, 4, 64));
      v = fmaxf(v, __shfl_xor(v, 8, 64));
      float mnew = fmaxf(m_i[r], v);
      alpha[r] = __expf(m_i[r] - mnew);
      m_i[r] = mnew;
    }
#pragma unroll
    for (int jn = 0; jn < 4; ++jn)
#pragma unroll
      for (int r = 0; r < 4; ++r) pv[jn][r] = __expf(pv[jn][r] - m_i[r]);
#pragma unroll
    for (int r = 0; r < 4; ++r) {
      float s = pv[0][r] + pv[1][r] + pv[2][r] + pv[3][r];
      s += __shfl_xor(s, 1, 64);
      s += __shfl_xor(s, 2, 64);
      s += __shfl_xor(s, 4, 64);
      s += __shfl_xor(s, 8, 64);
      l_i[r] = l_i[r] * alpha[r] + s;
    }
#pragma unroll
    for (int jn = 0; jn < 4; ++jn)
#pragma unroll
      for (int r = 0; r < 4; ++r)
        Ps[wid][quad * 4 + r][jn * 16 + l15] = f2bf(pv[jn][r]);
#pragma unroll
    for (int jd = 0; jd < 8; ++jd)
#pragma unroll
      for (int r = 0; r < 4; ++r) accO[jd][r] *= alpha[r];

    // per-wave Ps round-trip: drain this wave's ds_writes, block reordering
    __asm__ __volatile__("s_waitcnt lgkmcnt(0)" ::: "memory");

    short8 pf[2];
#pragma unroll
    for (int kk = 0; kk < 2; ++kk)
      pf[kk] = *(const short8*)&Ps[wid][l15][kk * 32 + quad * 8];
#pragma unroll
    for (int jd = 0; jd < 8; ++jd)
#pragma unroll
      for (int kk = 0; kk < 2; ++kk) {
        short8 vf = *(const short8*)&Vt[jd * 16 + l15][kk * 32 + quad * 8];
        accO[jd] = __builtin_amdgcn_mfma_f32_16x16x32_bf16(pf[kk], vf, accO[jd], 0, 0, 0);
      }
  }

#pragma unroll
  for (int jd = 0; jd < 8; ++jd)
#pragma unroll
    for (int r = 0; r < 4; ++r) {
      int row = b * S + qb + wid * 16 + quad * 4 + r;
      int col = h * D + jd * 16 + l15;
      ctx[(size_t)row * ldctx + col] = f2bf(accO[jd][r] / l_i[r]);
    }
}

// ---------------------------------------------------------------------------
extern "C" void kernel_launch(void* const* d_in, const int* in_sizes, int n_in,
                              void* d_out, int out_size, void* d_ws,
                              size_t ws_size, hipStream_t stream) {
  const float* x    = (const float*)d_in[0];
  const float* ln1  = (const float*)d_in[1];
  const float* Wq   = (const float*)d_in[2];
  const float* Wk   = (const float*)d_in[3];
  const float* Wv   = (const float*)d_in[4];
  const float* Wo   = (const float*)d_in[5];
  const float* ln2  = (const float*)d_in[6];
  const float* Wmlp = (const float*)d_in[7];
  const float* bmlp = (const float*)d_in[8];
  float* out = (float*)d_out;

  char* ws = (char*)d_ws;
  ushort_t* qkv = (ushort_t*)(ws + 0);         // [4096][6144] bf16
  ushort_t* R2  = (ushort_t*)(ws + 50331648);  // 16.78 MB rotating region
  ushort_t* WqT   = R2;                        // [2048][2048] bf16
  ushort_t* WkT   = R2 + 4194304;
  ushort_t* WvT   = R2;                        // reuse after Q GEMM
  ushort_t* vT    = R2;                        // [32][128][2048] after QKV
  ushort_t* WoT   = R2;                        // after attention
  ushort_t* WmlpT = R2;                        // after out-proj
  ushort_t* n1  = (ushort_t*)d_out;            // [4096][2048] bf16 scratch
  ushort_t* ctx = qkv + 4096;                  // V section, ld 6144
  ushort_t* x1  = qkv + 2048;                  // K section, ld 6144 (after attn)
  ushort_t* n2  = qkv;                         // Q section, ld 6144

  dim3 blk(256);
  dim3 tgrid(32, 32);
  dim3 ggrid(16, 32);

  // 1) rmsnorm1: x fp32 -> n1 bf16 (scratch in d_out)
  rmsnorm_kernel<false><<<dim3(4096), blk, 0, stream>>>(x, 2048, ln1, n1, 2048);

  // 2) Q,K GEMMs (weights transposed to bf16 [n][k] first)
  transpose_w_kernel<<<tgrid, blk, 0, stream>>>(Wq, WqT);
  transpose_w_kernel<<<tgrid, blk, 0, stream>>>(Wk, WkT);
  gemm_bt<0><<<ggrid, blk, 0, stream>>>(n1, 2048, WqT, 2048, qkv + 0, 6144,
                                        nullptr, 0, nullptr, 4096, 2048, 2048);
  gemm_bt<0><<<ggrid, blk, 0, stream>>>(n1, 2048, WkT, 2048, qkv + 2048, 6144,
                                        nullptr, 0, nullptr, 4096, 2048, 2048);
  // 3) V GEMM (WvT reuses WqT slot — Q GEMM done)
  transpose_w_kernel<<<tgrid, blk, 0, stream>>>(Wv, WvT);
  gemm_bt<0><<<ggrid, blk, 0, stream>>>(n1, 2048, WvT, 2048, qkv + 4096, 6144,
                                        nullptr, 0, nullptr, 4096, 2048, 2048);

  // 4) V transpose into R2 (weights dead)
  transpose_v_kernel<<<dim3(32, 2, 32), blk, 0, stream>>>(qkv, vT);

  // 5) causal flash attention -> ctx (overwrites dead V section)
  attn_kernel<<<dim3(32, 32), blk, 0, stream>>>(qkv, vT, ctx, 6144);

  // 6) out-projection + residual(x) -> x1 bf16 into dead K section
  transpose_w_kernel<<<tgrid, blk, 0, stream>>>(Wo, WoT);
  gemm_bt<1><<<ggrid, blk, 0, stream>>>(ctx, 6144, WoT, 2048, x1, 6144,
                                        x, 2048, nullptr, 4096, 2048, 2048);

  // 7) rmsnorm2: x1 -> n2 (dead Q section)
  rmsnorm_kernel<true><<<dim3(4096), blk, 0, stream>>>(x1, 6144, ln2, n2, 6144);

  // 8) MLP + residual(x1 bf16) + bias -> out fp32 (n1 dead)
  transpose_w_kernel<<<tgrid, blk, 0, stream>>>(Wmlp, WmlpT);
  gemm_bt<2><<<ggrid, blk, 0, stream>>>(n2, 6144, WmlpT, 2048, out, 2048,
                                        x1, 6144, bmlp, 4096, 2048, 2048);
}